// Round 21
// baseline (4588.173 us; speedup 1.0000x reference)
//
#include <hip/hip_runtime.h>

#define Bb 32
#define Tt 512
#define Ee 512
#define Hh 1024

typedef __attribute__((ext_vector_type(8))) short bf16x8;
typedef __attribute__((ext_vector_type(4))) float f32x4;
typedef __attribute__((ext_vector_type(4))) unsigned u32x4;
typedef unsigned long long u64;

#define SEN 0x7FC0u   // bf16 NaN; f2bf(finite h) can never produce it

__device__ __forceinline__ unsigned short f2bf(float f) {
  unsigned int u = __float_as_uint(f);
  u = (u + 0x7fffu + ((u >> 16) & 1u)) >> 16;
  return (unsigned short)u;
}
__device__ __forceinline__ float sigmoidf_(float x) {
  x = fminf(fmaxf(x, -30.f), 30.f);
  return 1.f / (1.f + __expf(-x));
}
__device__ __forceinline__ float tanh_fast(float x) {
  float xx = fminf(fmaxf(x, -15.f), 15.f);
  float e = __expf(2.f * xx);
  return (e - 1.f) / (e + 1.f);
}
__device__ __forceinline__ bool frag_bad(u32x4 v) {
  return ((v[0] & 0xFFFFu) == SEN) | ((v[1] & 0xFFFFu) == SEN) |
         ((v[2] & 0xFFFFu) == SEN) | ((v[3] & 0xFFFFu) == SEN);
}

// K1: gather embedding rows -> bf16; ring slot0 = zeros (h0),
// slots 1..511 = NaN sentinel.
__global__ void gather_kernel(const int* __restrict__ x,
                              const float* __restrict__ emb,
                              unsigned short* __restrict__ emb_hi,
                              unsigned short* __restrict__ hbuf) {
  long long gid = (long long)blockIdx.x * blockDim.x + threadIdx.x;
  long long stride = (long long)gridDim.x * blockDim.x;
  for (long long i = gid; i < 8192; i += stride)
    ((ushort4*)hbuf)[i] = make_ushort4(0, 0, 0, 0);
  for (long long i = 8192 + gid; i < 4194304; i += stride)
    ((ushort4*)hbuf)[i] =
        make_ushort4((unsigned short)SEN, (unsigned short)SEN,
                     (unsigned short)SEN, (unsigned short)SEN);
  long long n4 = (long long)Bb * Tt * Ee / 4;
  for (long long i = gid; i < n4; i += stride) {
    long long bt = i >> 7;
    int e4 = (int)(i & 127);
    int row = x[bt];
    row = min(max(row, 0), 31999);
    float4 v = ((const float4*)(emb + (long long)row * Ee))[e4];
    ushort4 hv;
    hv.x = f2bf(v.x); hv.y = f2bf(v.y);
    hv.z = f2bf(v.z); hv.w = f2bf(v.w);
    ((ushort4*)emb_hi)[i] = hv;
  }
}

// K2: persistent LSTM, 128 FAT WGs x 4 waves (R19 structure). WG owns 8
// units, j0 = (wg&7)*128 + (wg>>3)*8. Waves (kw,mt) K-split-2. Single-bf16
// weights. Pure dataflow: sentinel ring, plain burst, BATCHED pre-validation
// (issue all bad-fragment sc1 reloads back-to-back -> 16 serial RTTs become
// ~1-2 rounds), clean MFMA loop, fire-and-forget sc1 publish.
__global__ __launch_bounds__(256, 1)
void lstm_kernel(const unsigned short* __restrict__ emb_hi,
                 unsigned short* __restrict__ hbuf,
                 const float* __restrict__ W_ih,
                 const float* __restrict__ W_hh,
                 const float* __restrict__ b_ih,
                 const float* __restrict__ b_hh,
                 float* __restrict__ out) {
  __shared__ unsigned short sWih[32 * 512];    // 32 KB
  __shared__ unsigned short sWhh[32 * 1024];   // 64 KB
  __shared__ float sAcc[2][2][2][2][16][17];   // [par][kw][mt][bt][r][c] 34 KB
  __shared__ float sBias[32];
  __shared__ float sC[32][8];

  const int tid = threadIdx.x;
  const int lane = tid & 63;
  const int wv = tid >> 6;
  const int wg = blockIdx.x;
  const int j0 = (wg & 7) * 128 + (wg >> 3) * 8;

  // ---- stage W_ih slice (32 rows x 512) bf16, XOR-swizzled ----
  for (int idx = tid; idx < 32 * 64; idx += 256) {
    int c = idx >> 6, k8 = idx & 63;
    int grow = (c >> 3) * Hh + j0 + (c & 7);
    const float* src = W_ih + (long long)grow * Ee + k8 * 8;
    int us = (c * 512 + k8 * 8) ^ ((c & 7) << 3);
#pragma unroll
    for (int j = 0; j < 8; j++) sWih[us + j] = f2bf(src[j]);
  }
  // ---- stage W_hh slice (32 rows x 1024) ----
  for (int idx = tid; idx < 32 * 128; idx += 256) {
    int c = idx >> 7, k8 = idx & 127;
    int grow = (c >> 3) * Hh + j0 + (c & 7);
    const float* src = W_hh + (long long)grow * Hh + k8 * 8;
    int us = (c * 1024 + k8 * 8) ^ ((c & 7) << 3);
#pragma unroll
    for (int j = 0; j < 8; j++) sWhh[us + j] = f2bf(src[j]);
  }
  if (tid < 32) {
    int grow = (tid >> 3) * Hh + j0 + (tid & 7);
    sBias[tid] = b_ih[grow] + b_hh[grow];
  }
  sC[tid >> 3][tid & 7] = 0.f;
  __syncthreads();

  const int r16 = lane & 15;        // A-frag row within tile (batch)
  const int kg = (lane >> 4) * 8;   // k-offset in 32-chunk
  const int col = lane & 15;        // B-frag col
  const int kw = wv & 1;            // K-split half
  const int mt = wv >> 1;           // batch tile
  const int rb = mt * 16 + r16;     // global batch row

  float h_last = 0.f, c_last = 0.f;

  for (int t = 0; t < Tt; t++) {
    __builtin_amdgcn_sched_barrier(0);

    // ---- burst: 16 plain dwordx4 h loads (this wave's mt, K-half kw) ----
    const u32x4* hb4 = (const u32x4*)(hbuf + (u64)t * 32768);
    const u64* hb8 = (const u64*)(hbuf + (u64)t * 32768);
    u32x4 hA[16];
    int iA[16];
#pragma unroll
    for (int q = 0; q < 16; q++) {
      int kc = q * 2 + kw;
      iA[q] = (rb * Hh + kc * 32 + kg) >> 3;
      hA[q] = hb4[iA[q]];
    }

    // ---- x_proj (h loads in flight underneath) ----
    f32x4 acc[2];
    acc[0] = (f32x4){0.f, 0.f, 0.f, 0.f};
    acc[1] = (f32x4){0.f, 0.f, 0.f, 0.f};
#pragma unroll
    for (int q = 0; q < 8; q++) {
      int kc = q * 2 + kw;
      int ai = (rb * Tt + t) * Ee + kc * 32 + kg;
      bf16x8 aH = *(const bf16x8*)(emb_hi + ai);
#pragma unroll
      for (int bt = 0; bt < 2; bt++) {
        int c = bt * 16 + col;
        int bo = (c * 512 + kc * 32 + kg) ^ ((c & 7) << 3);
        bf16x8 bW = *(const bf16x8*)(sWih + bo);
        acc[bt] = __builtin_amdgcn_mfma_f32_16x16x32_bf16(aH, bW, acc[bt], 0, 0, 0);
      }
    }

    // ---- batched pre-validation: issue all bad reloads back-to-back ----
    unsigned badm = 0;
#pragma unroll
    for (int q = 0; q < 16; q++)
      if (frag_bad(hA[q])) badm |= 1u << q;
    while (__any(badm != 0u)) {
      u64 lA[16][2];
#pragma unroll
      for (int q = 0; q < 16; q++) {
        if (badm & (1u << q)) {
          lA[q][0] = __hip_atomic_load(hb8 + iA[q] * 2, __ATOMIC_RELAXED,
                                       __HIP_MEMORY_SCOPE_AGENT);
          lA[q][1] = __hip_atomic_load(hb8 + iA[q] * 2 + 1, __ATOMIC_RELAXED,
                                       __HIP_MEMORY_SCOPE_AGENT);
        }
      }
#pragma unroll
      for (int q = 0; q < 16; q++) {
        if (badm & (1u << q)) {
          u32x4 v;
          v[0] = (unsigned)lA[q][0]; v[1] = (unsigned)(lA[q][0] >> 32);
          v[2] = (unsigned)lA[q][1]; v[3] = (unsigned)(lA[q][1] >> 32);
          hA[q] = v;
          if (!frag_bad(v)) badm &= ~(1u << q);
        }
      }
    }

    // ---- recurrent MFMAs on clean fragments ----
#pragma unroll
    for (int q = 0; q < 16; q++) {
      int kc = q * 2 + kw;
      union { u32x4 u; bf16x8 v; } ua;
      ua.u = hA[q];
#pragma unroll
      for (int bt = 0; bt < 2; bt++) {
        int c = bt * 16 + col;
        int bo = (c * 1024 + kc * 32 + kg) ^ ((c & 7) << 3);
        bf16x8 bW = *(const bf16x8*)(sWhh + bo);
        acc[bt] = __builtin_amdgcn_mfma_f32_16x16x32_bf16(ua.v, bW, acc[bt], 0, 0, 0);
      }
    }

    // ---- K-split reduce via LDS (parity-double-buffered) ----
#pragma unroll
    for (int bt = 0; bt < 2; bt++)
#pragma unroll
      for (int r = 0; r < 4; r++)
        sAcc[t & 1][kw][mt][bt][(lane >> 4) * 4 + r][col] = acc[bt][r];
    __syncthreads();

    // ---- cell: all 256 threads, one (b, u) output each ----
    {
      int b = tid >> 3, u = tid & 7;
      int mtc = b >> 4, rr = b & 15;
      float g0 = sAcc[t & 1][0][mtc][0][rr][u] +
                 sAcc[t & 1][1][mtc][0][rr][u] + sBias[u];
      float g1 = sAcc[t & 1][0][mtc][0][rr][8 + u] +
                 sAcc[t & 1][1][mtc][0][rr][8 + u] + sBias[8 + u];
      float g2 = sAcc[t & 1][0][mtc][1][rr][u] +
                 sAcc[t & 1][1][mtc][1][rr][u] + sBias[16 + u];
      float g3 = sAcc[t & 1][0][mtc][1][rr][8 + u] +
                 sAcc[t & 1][1][mtc][1][rr][8 + u] + sBias[24 + u];
      float ig = sigmoidf_(g0);
      float fg = sigmoidf_(g1);
      float gg = tanh_fast(g2);
      float og = sigmoidf_(g3);
      float cn = fg * sC[b][u] + ig * gg;
      sC[b][u] = cn;
      float hn = og * tanh_fast(cn);
      h_last = hn; c_last = cn;

      // publish h[t+1]: fire-and-forget u32 sc1 stores
      unsigned pack = (unsigned)f2bf(hn);
      unsigned other = __shfl_xor(pack, 1, 64);
      if (t + 1 < Tt && (u & 1) == 0) {
        unsigned w = (pack & 0xffffu) | (other << 16);
        unsigned* nb32 = (unsigned*)(hbuf + (u64)(t + 1) * 32768);
        __hip_atomic_store(nb32 + ((b * 1024 + j0 + u) >> 1), w,
                           __ATOMIC_RELAXED, __HIP_MEMORY_SCOPE_AGENT);
      }
      out[((long long)b * Tt + t) * Hh + j0 + u] = hn;
    }
    // no tail barrier: sAcc parity-buffered; ring slots never reused
  }

  {
    int b = tid >> 3, u = tid & 7;
    int hj = j0 + u;
    out[16777216LL + b * Hh + hj] = h_last;           // state_h
    out[16777216LL + 32768 + b * Hh + hj] = c_last;   // state_c
  }
}

extern "C" void kernel_launch(void* const* d_in, const int* in_sizes, int n_in,
                              void* d_out, int out_size, void* d_ws, size_t ws_size,
                              hipStream_t stream) {
  const int* x      = (const int*)d_in[0];
  const float* emb  = (const float*)d_in[1];
  const float* W_ih = (const float*)d_in[2];
  const float* W_hh = (const float*)d_in[3];
  const float* b_ih = (const float*)d_in[4];
  const float* b_hh = (const float*)d_in[5];
  float* out = (float*)d_out;

  unsigned short* emb_hi = (unsigned short*)d_ws;      // 16 MB
  unsigned short* hbuf   = emb_hi + 8388608;           // 512-slot ring, 32 MB

  hipLaunchKernelGGL(gather_kernel, dim3(2048), dim3(256), 0, stream,
                     x, emb, emb_hi, hbuf);

  void* args[] = { (void*)&emb_hi, (void*)&hbuf,
                   (void*)&W_ih, (void*)&W_hh, (void*)&b_ih, (void*)&b_hh,
                   (void*)&out };
  // No grid.sync(); cooperative launch is a co-residency hint only.
  hipError_t e = hipLaunchCooperativeKernel((void*)lstm_kernel, dim3(128),
                                            dim3(256), args, 0, stream);
  if (e != hipSuccess) {
    hipLaunchKernelGGL(lstm_kernel, dim3(128), dim3(256), 0, stream,
                       emb_hi, hbuf, W_ih, W_hh, b_ih, b_hh, out);
  }
}

// Round 22
// 2853.179 us; speedup vs baseline: 1.6081x; 1.6081x over previous
//
#include <hip/hip_runtime.h>

#define Bb 32
#define Tt 512
#define Ee 512
#define Hh 1024

typedef __attribute__((ext_vector_type(8))) short bf16x8;
typedef __attribute__((ext_vector_type(4))) float f32x4;
typedef __attribute__((ext_vector_type(4))) unsigned u32x4;
typedef unsigned long long u64;

#define SEN 0x7FC0u   // bf16 NaN; f2bf(finite h) can never produce it

__device__ __forceinline__ unsigned short f2bf(float f) {
  unsigned int u = __float_as_uint(f);
  u = (u + 0x7fffu + ((u >> 16) & 1u)) >> 16;
  return (unsigned short)u;
}
__device__ __forceinline__ float sigmoidf_(float x) {
  x = fminf(fmaxf(x, -30.f), 30.f);
  return 1.f / (1.f + __expf(-x));
}
__device__ __forceinline__ float tanh_fast(float x) {
  float xx = fminf(fmaxf(x, -15.f), 15.f);
  float e = __expf(2.f * xx);
  return (e - 1.f) / (e + 1.f);
}
__device__ __forceinline__ bool frag_bad(u32x4 v) {
  return ((v[0] & 0xFFFFu) == SEN) | ((v[1] & 0xFFFFu) == SEN) |
         ((v[2] & 0xFFFFu) == SEN) | ((v[3] & 0xFFFFu) == SEN);
}

// K1: gather embedding rows -> bf16 (hi only); ring slot0 = zeros (h0),
// slots 1..511 = NaN sentinel.
__global__ void gather_kernel(const int* __restrict__ x,
                              const float* __restrict__ emb,
                              unsigned short* __restrict__ emb_hi,
                              unsigned short* __restrict__ hbuf) {
  long long gid = (long long)blockIdx.x * blockDim.x + threadIdx.x;
  long long stride = (long long)gridDim.x * blockDim.x;
  for (long long i = gid; i < 8192; i += stride)
    ((ushort4*)hbuf)[i] = make_ushort4(0, 0, 0, 0);
  for (long long i = 8192 + gid; i < 4194304; i += stride)
    ((ushort4*)hbuf)[i] =
        make_ushort4((unsigned short)SEN, (unsigned short)SEN,
                     (unsigned short)SEN, (unsigned short)SEN);
  long long n4 = (long long)Bb * Tt * Ee / 4;
  for (long long i = gid; i < n4; i += stride) {
    long long bt = i >> 7;
    int e4 = (int)(i & 127);
    int row = x[bt];
    row = min(max(row, 0), 31999);
    float4 v = ((const float4*)(emb + (long long)row * Ee))[e4];
    ushort4 hv;
    hv.x = f2bf(v.x); hv.y = f2bf(v.y);
    hv.z = f2bf(v.z); hv.w = f2bf(v.w);
    ((ushort4*)emb_hi)[i] = hv;
  }
}

// K2: persistent LSTM, 128 FAT WGs x 4 waves. WG owns 8 units j0..j0+7
// (32 gate-rows), j0 = (wg&7)*128 + (wg>>3)*8. Wave (kw,mt) = (wv&1,wv>>1):
// K-split 2 within its batch-tile mt. Broadcast traffic 8 MB/step.
// Pure dataflow (R16-proven): sentinel ring, plain burst + per-fragment sc1
// spin (overlapped with recurrent MFMAs), fire-and-forget sc1 publish,
// parity-buffered sAcc, one barrier per step.
__global__ __launch_bounds__(256, 1)
void lstm_kernel(const unsigned short* __restrict__ emb_hi,
                 unsigned short* __restrict__ hbuf,
                 const float* __restrict__ W_ih,
                 const float* __restrict__ W_hh,
                 const float* __restrict__ b_ih,
                 const float* __restrict__ b_hh,
                 float* __restrict__ out) {
  __shared__ unsigned short sWih[32 * 512];    // 32 KB
  __shared__ unsigned short sWhh[32 * 1024];   // 64 KB
  __shared__ float sAcc[2][2][2][2][16][17];   // [par][kw][mt][bt][r][c] 34 KB
  __shared__ float sBias[32];
  __shared__ float sC[32][8];

  const int tid = threadIdx.x;
  const int lane = tid & 63;
  const int wv = tid >> 6;
  const int wg = blockIdx.x;
  const int j0 = (wg & 7) * 128 + (wg >> 3) * 8;

  // ---- stage W_ih slice (32 rows x 512) bf16, XOR-swizzled ----
  for (int idx = tid; idx < 32 * 64; idx += 256) {
    int c = idx >> 6, k8 = idx & 63;
    int grow = (c >> 3) * Hh + j0 + (c & 7);
    const float* src = W_ih + (long long)grow * Ee + k8 * 8;
    int us = (c * 512 + k8 * 8) ^ ((c & 7) << 3);
#pragma unroll
    for (int j = 0; j < 8; j++) sWih[us + j] = f2bf(src[j]);
  }
  // ---- stage W_hh slice (32 rows x 1024) ----
  for (int idx = tid; idx < 32 * 128; idx += 256) {
    int c = idx >> 7, k8 = idx & 127;
    int grow = (c >> 3) * Hh + j0 + (c & 7);
    const float* src = W_hh + (long long)grow * Hh + k8 * 8;
    int us = (c * 1024 + k8 * 8) ^ ((c & 7) << 3);
#pragma unroll
    for (int j = 0; j < 8; j++) sWhh[us + j] = f2bf(src[j]);
  }
  if (tid < 32) {
    int grow = (tid >> 3) * Hh + j0 + (tid & 7);
    sBias[tid] = b_ih[grow] + b_hh[grow];
  }
  sC[tid >> 3][tid & 7] = 0.f;
  __syncthreads();

  const int r16 = lane & 15;        // A-frag row within tile (batch)
  const int kg = (lane >> 4) * 8;   // k-offset in 32-chunk
  const int col = lane & 15;        // B-frag col
  const int kw = wv & 1;            // K-split half
  const int mt = wv >> 1;           // batch tile
  const int rb = mt * 16 + r16;     // global batch row

  float h_last = 0.f, c_last = 0.f;

  for (int t = 0; t < Tt; t++) {
    __builtin_amdgcn_sched_barrier(0);

    // ---- burst: 16 plain dwordx4 h loads (this wave's mt, K-half kw) ----
    const u32x4* hb4 = (const u32x4*)(hbuf + (u64)t * 32768);
    const u64* hb8 = (const u64*)(hbuf + (u64)t * 32768);
    u32x4 hA[16];
    int iA[16];
#pragma unroll
    for (int q = 0; q < 16; q++) {
      int kc = q * 2 + kw;
      iA[q] = (rb * Hh + kc * 32 + kg) >> 3;
      hA[q] = hb4[iA[q]];
    }

    // ---- x_proj (emb hi x W_ih hi; h loads in flight underneath) ----
    f32x4 acc[2];
    acc[0] = (f32x4){0.f, 0.f, 0.f, 0.f};
    acc[1] = (f32x4){0.f, 0.f, 0.f, 0.f};
#pragma unroll
    for (int q = 0; q < 8; q++) {
      int kc = q * 2 + kw;
      int ai = (rb * Tt + t) * Ee + kc * 32 + kg;
      bf16x8 aH = *(const bf16x8*)(emb_hi + ai);
#pragma unroll
      for (int bt = 0; bt < 2; bt++) {
        int c = bt * 16 + col;
        int bo = (c * 512 + kc * 32 + kg) ^ ((c & 7) << 3);
        bf16x8 bW = *(const bf16x8*)(sWih + bo);
        acc[bt] = __builtin_amdgcn_mfma_f32_16x16x32_bf16(aH, bW, acc[bt], 0, 0, 0);
      }
    }

    // ---- validate per fragment (sc1 spin) + recurrent MFMAs ----
#pragma unroll
    for (int q = 0; q < 16; q++) {
      int kc = q * 2 + kw;
      u32x4 va = hA[q];
      bool bad = frag_bad(va);
      while (__any(bad)) {
        if (bad) {
          u64 a0 = __hip_atomic_load(hb8 + iA[q] * 2, __ATOMIC_RELAXED,
                                     __HIP_MEMORY_SCOPE_AGENT);
          u64 a1 = __hip_atomic_load(hb8 + iA[q] * 2 + 1, __ATOMIC_RELAXED,
                                     __HIP_MEMORY_SCOPE_AGENT);
          va[0] = (unsigned)a0; va[1] = (unsigned)(a0 >> 32);
          va[2] = (unsigned)a1; va[3] = (unsigned)(a1 >> 32);
        }
        bad = frag_bad(va);
      }
      union { u32x4 u; bf16x8 v; } ua;
      ua.u = va;
#pragma unroll
      for (int bt = 0; bt < 2; bt++) {
        int c = bt * 16 + col;
        int bo = (c * 1024 + kc * 32 + kg) ^ ((c & 7) << 3);
        bf16x8 bW = *(const bf16x8*)(sWhh + bo);
        acc[bt] = __builtin_amdgcn_mfma_f32_16x16x32_bf16(ua.v, bW, acc[bt], 0, 0, 0);
      }
    }

    // ---- K-split reduce via LDS (parity-double-buffered) ----
#pragma unroll
    for (int bt = 0; bt < 2; bt++)
#pragma unroll
      for (int r = 0; r < 4; r++)
        sAcc[t & 1][kw][mt][bt][(lane >> 4) * 4 + r][col] = acc[bt][r];
    __syncthreads();

    // ---- cell: all 256 threads, one (b, u) output each ----
    {
      int b = tid >> 3, u = tid & 7;
      int mtc = b >> 4, rr = b & 15;
      float g0 = sAcc[t & 1][0][mtc][0][rr][u] +
                 sAcc[t & 1][1][mtc][0][rr][u] + sBias[u];
      float g1 = sAcc[t & 1][0][mtc][0][rr][8 + u] +
                 sAcc[t & 1][1][mtc][0][rr][8 + u] + sBias[8 + u];
      float g2 = sAcc[t & 1][0][mtc][1][rr][u] +
                 sAcc[t & 1][1][mtc][1][rr][u] + sBias[16 + u];
      float g3 = sAcc[t & 1][0][mtc][1][rr][8 + u] +
                 sAcc[t & 1][1][mtc][1][rr][8 + u] + sBias[24 + u];
      float ig = sigmoidf_(g0);
      float fg = sigmoidf_(g1);
      float gg = tanh_fast(g2);
      float og = sigmoidf_(g3);
      float cn = fg * sC[b][u] + ig * gg;
      sC[b][u] = cn;
      float hn = og * tanh_fast(cn);
      h_last = hn; c_last = cn;

      // publish h[t+1]: fire-and-forget u32 sc1 stores
      unsigned pack = (unsigned)f2bf(hn);
      unsigned other = __shfl_xor(pack, 1, 64);
      if (t + 1 < Tt && (u & 1) == 0) {
        unsigned w = (pack & 0xffffu) | (other << 16);
        unsigned* nb32 = (unsigned*)(hbuf + (u64)(t + 1) * 32768);
        __hip_atomic_store(nb32 + ((b * 1024 + j0 + u) >> 1), w,
                           __ATOMIC_RELAXED, __HIP_MEMORY_SCOPE_AGENT);
      }
      out[((long long)b * Tt + t) * Hh + j0 + u] = hn;
    }
    // no tail barrier: sAcc parity-buffered; ring slots never reused
  }

  {
    int b = tid >> 3, u = tid & 7;
    int hj = j0 + u;
    out[16777216LL + b * Hh + hj] = h_last;           // state_h
    out[16777216LL + 32768 + b * Hh + hj] = c_last;   // state_c
  }
}

extern "C" void kernel_launch(void* const* d_in, const int* in_sizes, int n_in,
                              void* d_out, int out_size, void* d_ws, size_t ws_size,
                              hipStream_t stream) {
  const int* x      = (const int*)d_in[0];
  const float* emb  = (const float*)d_in[1];
  const float* W_ih = (const float*)d_in[2];
  const float* W_hh = (const float*)d_in[3];
  const float* b_ih = (const float*)d_in[4];
  const float* b_hh = (const float*)d_in[5];
  float* out = (float*)d_out;

  unsigned short* emb_hi = (unsigned short*)d_ws;      // 16 MB
  unsigned short* hbuf   = emb_hi + 8388608;           // 512-slot ring, 32 MB

  hipLaunchKernelGGL(gather_kernel, dim3(2048), dim3(256), 0, stream,
                     x, emb, emb_hi, hbuf);

  void* args[] = { (void*)&emb_hi, (void*)&hbuf,
                   (void*)&W_ih, (void*)&W_hh, (void*)&b_ih, (void*)&b_hh,
                   (void*)&out };
  // No grid.sync(); cooperative launch is a co-residency hint only.
  hipError_t e = hipLaunchCooperativeKernel((void*)lstm_kernel, dim3(128),
                                            dim3(256), args, 0, stream);
  if (e != hipSuccess) {
    hipLaunchKernelGGL(lstm_kernel, dim3(128), dim3(256), 0, stream,
                       emb_hi, hbuf, W_ih, W_hh, b_ih, b_hh, out);
  }
}